// Round 1
// baseline (2224.835 us; speedup 1.0000x reference)
//
#include <hip/hip_runtime.h>

typedef _Float16 f16;
typedef _Float16 f16x2 __attribute__((ext_vector_type(2)));
typedef _Float16 f16x4 __attribute__((ext_vector_type(4)));
typedef _Float16 f16x8 __attribute__((ext_vector_type(8)));
typedef float    f32x4 __attribute__((ext_vector_type(4)));

__device__ __forceinline__ float fdot2(f16x2 a, f16x2 b, float c) {
#if __has_builtin(__builtin_amdgcn_fdot2)
  return __builtin_amdgcn_fdot2(a, b, c, false);
#else
  return c + (float)a[0] * (float)b[0] + (float)a[1] * (float)b[1];
#endif
}

// ---------------- small helper kernels ----------------

__global__ void cvt_f32_to_f16(const float* __restrict__ in, f16* __restrict__ out, int n) {
  int i = (blockIdx.x * blockDim.x + threadIdx.x) * 4;
  if (i + 3 < n) {
    float4 v = *(const float4*)(in + i);
    f16x4 h; h[0] = (f16)v.x; h[1] = (f16)v.y; h[2] = (f16)v.z; h[3] = (f16)v.w;
    *(f16x4*)(out + i) = h;
  }
}

__global__ void bias_comb_kernel(const float* __restrict__ a, const float* __restrict__ b,
                                 float* __restrict__ o, int n) {
  int i = blockIdx.x * blockDim.x + threadIdx.x;
  if (i < n) o[i] = a[i] + b[i];
}

// ---------------- GEMM: C[M,N] = A[M,K] * B[N,K]^T + bias[N] ----------------
// A is f32 (converted on the fly) or f16; B is f16 [N][K] row-major; C is f32.
// Tile 128x128, BK=32, 256 threads = 4 waves in 2x2, each wave does 64x64 via
// 4x4 frags of mfma_f32_16x16x32_f16.

#define BM 128
#define BN 128
#define BKT 32
#define LDK 40  // padded leading dim (f16 elems) to dodge bank conflicts

template <bool A_IS_F32>
__global__ __launch_bounds__(256, 2) void gemm_f16_kernel(
    const void* __restrict__ Aptr,    // [M][K]
    const f16* __restrict__ B,        // [N][K]
    const float* __restrict__ bias,   // [N]
    float* __restrict__ C,            // [M][N]
    int M, int N, int K) {
  __shared__ f16 As[BM][LDK];
  __shared__ f16 Bs[BN][LDK];

  const int tid = threadIdx.x;
  const int bm = blockIdx.y, bn = blockIdx.x;
  const int wave = tid >> 6, lane = tid & 63;
  const int wm = wave >> 1, wn = wave & 1;

  f32x4 acc[4][4] = {};

  for (int k0 = 0; k0 < K; k0 += BKT) {
    // ---- stage A and B tiles (each thread: 2 iters x 8 f16) ----
#pragma unroll
    for (int it = 0; it < 2; ++it) {
      int idx = tid + it * 256;          // 0..511
      int row = idx >> 2;                // 0..127
      int kc  = (idx & 3) << 3;          // 0,8,16,24
      if (A_IS_F32) {
        const float* Af = (const float*)Aptr + (size_t)(bm * BM + row) * K + k0 + kc;
        float4 v0 = *(const float4*)Af;
        float4 v1 = *(const float4*)(Af + 4);
        f16x8 h;
        h[0] = (f16)v0.x; h[1] = (f16)v0.y; h[2] = (f16)v0.z; h[3] = (f16)v0.w;
        h[4] = (f16)v1.x; h[5] = (f16)v1.y; h[6] = (f16)v1.z; h[7] = (f16)v1.w;
        *(f16x8*)&As[row][kc] = h;
      } else {
        const f16* Ah = (const f16*)Aptr + (size_t)(bm * BM + row) * K + k0 + kc;
        *(f16x8*)&As[row][kc] = *(const f16x8*)Ah;
      }
      const f16* Bh = B + (size_t)(bn * BN + row) * K + k0 + kc;
      *(f16x8*)&Bs[row][kc] = *(const f16x8*)Bh;
    }
    __syncthreads();

    // ---- fragments + MFMA ----
    const int fr = lane & 15;
    const int fk = (lane >> 4) << 3;  // 0,8,16,24
    f16x8 af[4], bf[4];
#pragma unroll
    for (int i = 0; i < 4; ++i) af[i] = *(const f16x8*)&As[wm * 64 + i * 16 + fr][fk];
#pragma unroll
    for (int j = 0; j < 4; ++j) bf[j] = *(const f16x8*)&Bs[wn * 64 + j * 16 + fr][fk];
#pragma unroll
    for (int i = 0; i < 4; ++i)
#pragma unroll
      for (int j = 0; j < 4; ++j)
        acc[i][j] = __builtin_amdgcn_mfma_f32_16x16x32_f16(af[i], bf[j], acc[i][j], 0, 0, 0);
    __syncthreads();
  }

  // ---- epilogue: D layout col=lane&15, row=(lane>>4)*4+r ----
  const int fr = lane & 15;
  const int fq = lane >> 4;
#pragma unroll
  for (int i = 0; i < 4; ++i)
#pragma unroll
    for (int j = 0; j < 4; ++j)
#pragma unroll
      for (int r = 0; r < 4; ++r) {
        int row = bm * BM + wm * 64 + i * 16 + fq * 4 + r;
        int col = bn * BN + wn * 64 + j * 16 + fr;
        C[(size_t)row * N + col] = acc[i][j][r] + bias[col];
      }
}

// ---------------- recurrent scan ----------------
// One block per batch row. W_hh row `tid` (512 f16): k in [0,384) in VGPRs
// (48 x f16x8 = 192 VGPRs), k in [384,512) in LDS laid out [chunk][tid]
// (conflict-free: bank = tid % 32, 2 lanes/bank = free).
// h lives in LDS (f16, double-buffered); reads are uniform-address broadcasts.

#define RT 512
#define KREGC 48   // 48 chunks of 8 f16 = 384 k in registers
#define KLDSC 16   // 16 chunks of 8 f16 = 128 k in LDS

__global__ __launch_bounds__(RT, 2) void rnn_scan_kernel(
    const f16* __restrict__ Whh,    // [512][512] f16
    const float* __restrict__ h0,   // [B][512] f32
    const float* __restrict__ xp,   // [B][T][512] f32 (pre-activation incl. biases)
    f16* __restrict__ hs,           // [B][T][512] f16 (out, for y-GEMM)
    float* __restrict__ hn,         // [B][512] f32 (out)
    int T) {
  __shared__ f16x2 Wl[KLDSC * 4][RT];            // 64 x 512 x 4B = 128 KB
  __shared__ __align__(16) f16 hbuf[2][512];     // 2 KB

  const int tid = threadIdx.x;
  const int b = blockIdx.x;

  // load my W_hh row
  const f16x8* wrow8 = (const f16x8*)(Whh + (size_t)tid * 512);
  f16x8 wreg[KREGC];
#pragma unroll
  for (int i = 0; i < KREGC; ++i) wreg[i] = wrow8[i];
#pragma unroll
  for (int i = 0; i < KLDSC; ++i) {
    union { f16x8 v; f16x2 p[4]; } u;
    u.v = wrow8[KREGC + i];
    Wl[i * 4 + 0][tid] = u.p[0];
    Wl[i * 4 + 1][tid] = u.p[1];
    Wl[i * 4 + 2][tid] = u.p[2];
    Wl[i * 4 + 3][tid] = u.p[3];
  }
  hbuf[0][tid] = (f16)h0[(size_t)b * 512 + tid];
  __syncthreads();

  const float* xpb = xp + (size_t)b * T * 512 + tid;
  f16* hsb = hs + (size_t)b * T * 512 + tid;

  int cur = 0;
  float hlast = 0.f;
  for (int t = 0; t < T; ++t) {
    float a0 = xpb[(size_t)t * 512];
    float a1 = 0.f, a2 = 0.f, a3 = 0.f;
    const f16x8* h8 = (const f16x8*)hbuf[cur];
#pragma unroll
    for (int i = 0; i < KREGC; ++i) {
      union { f16x8 v; f16x2 p[4]; } hu, wu;
      hu.v = h8[i];               // uniform address -> LDS broadcast (b128)
      wu.v = wreg[i];
      a0 = fdot2(wu.p[0], hu.p[0], a0);
      a1 = fdot2(wu.p[1], hu.p[1], a1);
      a2 = fdot2(wu.p[2], hu.p[2], a2);
      a3 = fdot2(wu.p[3], hu.p[3], a3);
    }
#pragma unroll
    for (int i = 0; i < KLDSC; ++i) {
      union { f16x8 v; f16x2 p[4]; } hu;
      hu.v = h8[KREGC + i];
      a0 = fdot2(Wl[i * 4 + 0][tid], hu.p[0], a0);
      a1 = fdot2(Wl[i * 4 + 1][tid], hu.p[1], a1);
      a2 = fdot2(Wl[i * 4 + 2][tid], hu.p[2], a2);
      a3 = fdot2(Wl[i * 4 + 3][tid], hu.p[3], a3);
    }
    float acc = (a0 + a1) + (a2 + a3);
    float hnew = tanhf(acc);
    hlast = hnew;
    f16 hh = (f16)hnew;
    hsb[(size_t)t * 512] = hh;
    hbuf[cur ^ 1][tid] = hh;
    __syncthreads();
    cur ^= 1;
  }
  hn[(size_t)b * 512 + tid] = hlast;
}

// ---------------- launch ----------------

extern "C" void kernel_launch(void* const* d_in, const int* in_sizes, int n_in,
                              void* d_out, int out_size, void* d_ws, size_t ws_size,
                              hipStream_t stream) {
  const float* x    = (const float*)d_in[0];
  const float* h0   = (const float*)d_in[1];
  const float* W_xh = (const float*)d_in[2];
  const float* b_xh = (const float*)d_in[3];
  const float* W_hh = (const float*)d_in[4];
  const float* b_hh = (const float*)d_in[5];
  const float* W_hy = (const float*)d_in[6];
  const float* b_hy = (const float*)d_in[7];

  const int H = 512;
  const int B = in_sizes[1] / H;            // 64
  const int T = in_sizes[0] / (B * H);      // 1024
  const int M = B * T;                      // 65536

  float* out = (float*)d_out;               // y [M][512] then h_n [B][512]
  float* xp  = out;                         // reuse y region as xp scratch
  float* hn  = out + (size_t)M * H;

  char* w = (char*)d_ws;
  f16*   hs     = (f16*)w;                                  // M*H*2 bytes
  f16*   Wxh_h  = (f16*)(w + (size_t)M * H * 2);
  f16*   Whh_h  = Wxh_h + H * H;
  f16*   Why_h  = Whh_h + H * H;
  float* biasc  = (float*)(Why_h + H * H);

  const int WN = H * H;  // 262144
  cvt_f32_to_f16<<<WN / 1024, 256, 0, stream>>>(W_xh, Wxh_h, WN);
  cvt_f32_to_f16<<<WN / 1024, 256, 0, stream>>>(W_hh, Whh_h, WN);
  cvt_f32_to_f16<<<WN / 1024, 256, 0, stream>>>(W_hy, Why_h, WN);
  bias_comb_kernel<<<2, 256, 0, stream>>>(b_xh, b_hh, biasc, H);

  // xp = x @ W_xh^T + (b_xh + b_hh)   (written into d_out)
  gemm_f16_kernel<true><<<dim3(H / BN, M / BM), 256, 0, stream>>>(
      x, Wxh_h, biasc, xp, M, H, H);

  // sequential scan; writes hs (f16, ws) and h_n (f32, d_out tail)
  rnn_scan_kernel<<<B, RT, 0, stream>>>(Whh_h, h0, xp, hs, hn, T);

  // y = hs @ W_hy^T + b_hy   (overwrites xp region of d_out)
  gemm_f16_kernel<false><<<dim3(H / BN, M / BM), 256, 0, stream>>>(
      hs, Why_h, b_hy, out, M, H, H);
}

// Round 2
// 1854.508 us; speedup vs baseline: 1.1997x; 1.1997x over previous
//
#include <hip/hip_runtime.h>

typedef _Float16 f16;
typedef _Float16 f16x2 __attribute__((ext_vector_type(2)));
typedef _Float16 f16x4 __attribute__((ext_vector_type(4)));
typedef _Float16 f16x8 __attribute__((ext_vector_type(8)));
typedef float    f32x4 __attribute__((ext_vector_type(4)));

__device__ __forceinline__ float fdot2(f16x2 a, f16x2 b, float c) {
#if __has_builtin(__builtin_amdgcn_fdot2)
  return __builtin_amdgcn_fdot2(a, b, c, false);
#else
  return c + (float)a[0] * (float)b[0] + (float)a[1] * (float)b[1];
#endif
}

// ---------------- small helper kernels ----------------

__global__ void cvt_f32_to_f16(const float* __restrict__ in, f16* __restrict__ out, int n) {
  int i = (blockIdx.x * blockDim.x + threadIdx.x) * 4;
  if (i + 3 < n) {
    float4 v = *(const float4*)(in + i);
    f16x4 h; h[0] = (f16)v.x; h[1] = (f16)v.y; h[2] = (f16)v.z; h[3] = (f16)v.w;
    *(f16x4*)(out + i) = h;
  }
}

__global__ void bias_comb_kernel(const float* __restrict__ a, const float* __restrict__ b,
                                 float* __restrict__ o, int n) {
  int i = blockIdx.x * blockDim.x + threadIdx.x;
  if (i < n) o[i] = a[i] + b[i];
}

// ---------------- GEMM: C[M,N] = A[M,K] * B[N,K]^T + bias[N] ----------------

#define BM 128
#define BN 128
#define BKT 32
#define LDK 40  // padded leading dim (f16 elems) to dodge bank conflicts

template <bool A_IS_F32>
__global__ __launch_bounds__(256, 2) void gemm_f16_kernel(
    const void* __restrict__ Aptr,    // [M][K]
    const f16* __restrict__ B,        // [N][K]
    const float* __restrict__ bias,   // [N]
    float* __restrict__ C,            // [M][N]
    int M, int N, int K) {
  __shared__ f16 As[BM][LDK];
  __shared__ f16 Bs[BN][LDK];

  const int tid = threadIdx.x;
  const int bm = blockIdx.y, bn = blockIdx.x;
  const int wave = tid >> 6, lane = tid & 63;
  const int wm = wave >> 1, wn = wave & 1;

  f32x4 acc[4][4] = {};

  for (int k0 = 0; k0 < K; k0 += BKT) {
#pragma unroll
    for (int it = 0; it < 2; ++it) {
      int idx = tid + it * 256;          // 0..511
      int row = idx >> 2;                // 0..127
      int kc  = (idx & 3) << 3;          // 0,8,16,24
      if (A_IS_F32) {
        const float* Af = (const float*)Aptr + (size_t)(bm * BM + row) * K + k0 + kc;
        float4 v0 = *(const float4*)Af;
        float4 v1 = *(const float4*)(Af + 4);
        f16x8 h;
        h[0] = (f16)v0.x; h[1] = (f16)v0.y; h[2] = (f16)v0.z; h[3] = (f16)v0.w;
        h[4] = (f16)v1.x; h[5] = (f16)v1.y; h[6] = (f16)v1.z; h[7] = (f16)v1.w;
        *(f16x8*)&As[row][kc] = h;
      } else {
        const f16* Ah = (const f16*)Aptr + (size_t)(bm * BM + row) * K + k0 + kc;
        *(f16x8*)&As[row][kc] = *(const f16x8*)Ah;
      }
      const f16* Bh = B + (size_t)(bn * BN + row) * K + k0 + kc;
      *(f16x8*)&Bs[row][kc] = *(const f16x8*)Bh;
    }
    __syncthreads();

    const int fr = lane & 15;
    const int fk = (lane >> 4) << 3;  // 0,8,16,24
    f16x8 af[4], bf[4];
#pragma unroll
    for (int i = 0; i < 4; ++i) af[i] = *(const f16x8*)&As[wm * 64 + i * 16 + fr][fk];
#pragma unroll
    for (int j = 0; j < 4; ++j) bf[j] = *(const f16x8*)&Bs[wn * 64 + j * 16 + fr][fk];
#pragma unroll
    for (int i = 0; i < 4; ++i)
#pragma unroll
      for (int j = 0; j < 4; ++j)
        acc[i][j] = __builtin_amdgcn_mfma_f32_16x16x32_f16(af[i], bf[j], acc[i][j], 0, 0, 0);
    __syncthreads();
  }

  const int fr = lane & 15;
  const int fq = lane >> 4;
#pragma unroll
  for (int i = 0; i < 4; ++i)
#pragma unroll
    for (int j = 0; j < 4; ++j)
#pragma unroll
      for (int r = 0; r < 4; ++r) {
        int row = bm * BM + wm * 64 + i * 16 + fq * 4 + r;
        int col = bn * BN + wn * 64 + j * 16 + fr;
        C[(size_t)row * N + col] = acc[i][j][r] + bias[col];
      }
}

// ---------------- recurrent scan ----------------
// One block (512 threads, 1 block/CU) per batch row; thread tid owns output tid.
// W_hh row tid: k in [0,416) in VGPRs (52 x f16x8 = 208 VGPRs, 256-cap via
// __launch_bounds__(512,1) so NO AGPR bouncing), k in [416,512) in LDS as
// f16x2 [chunk][tid] (bank = tid%32, 2 lanes/bank = conflict-free).
// h double-buffered in LDS; h reads are wave-uniform b128 broadcasts.
// xp prefetched one step ahead; tanh via exp+rcp (branch-free, TRANS pipe).

#define RT 512
#define KREGC 52   // 52 chunks of 8 f16 = 416 k in registers
#define KLDSC 12   // 12 chunks of 8 f16 =  96 k in LDS

__global__ __launch_bounds__(RT, 1) void rnn_scan_kernel(
    const f16* __restrict__ Whh,    // [512][512] f16
    const float* __restrict__ h0,   // [B][512] f32
    const float* __restrict__ xp,   // [B][T][512] f32 (pre-activation incl. biases)
    f16* __restrict__ hs,           // [B][T][512] f16 (out, for y-GEMM)
    float* __restrict__ hn,         // [B][512] f32 (out)
    int T) {
  __shared__ f16x2 Wl[KLDSC * 4][RT];            // 48 x 512 x 4B = 96 KB
  __shared__ __align__(16) f16 hbuf[2][RT];      // 2 KB

  const int tid = threadIdx.x;
  const int b = blockIdx.x;

  const f16x8* wrow8 = (const f16x8*)(Whh + (size_t)tid * 512);
  f16x8 wreg[KREGC];
#pragma unroll
  for (int i = 0; i < KREGC; ++i) wreg[i] = wrow8[i];
#pragma unroll
  for (int i = 0; i < KLDSC; ++i) {
    union { f16x8 v; f16x2 p[4]; } u;
    u.v = wrow8[KREGC + i];
    Wl[i * 4 + 0][tid] = u.p[0];
    Wl[i * 4 + 1][tid] = u.p[1];
    Wl[i * 4 + 2][tid] = u.p[2];
    Wl[i * 4 + 3][tid] = u.p[3];
  }
  hbuf[0][tid] = (f16)h0[(size_t)b * 512 + tid];
  __syncthreads();

  const float* xpb = xp + (size_t)b * T * 512 + tid;
  f16* hsb = hs + (size_t)b * T * 512 + tid;

  int cur = 0;
  float hlast = 0.f;
  float xv = xpb[0];
  for (int t = 0; t < T; ++t) {
    // prefetch next step's xp (clamped; independent of this step's compute)
    int tn = t + 1 < T ? t + 1 : t;
    float xn = xpb[(size_t)tn * 512];

    float a0 = xv, a1 = 0.f, a2 = 0.f, a3 = 0.f;
    const f16x8* h8 = (const f16x8*)hbuf[cur];
#pragma unroll
    for (int i = 0; i < KREGC; ++i) {
      union { f16x8 v; f16x2 p[4]; } hu, wu;
      hu.v = h8[i];               // uniform address -> LDS broadcast
      wu.v = wreg[i];
      a0 = fdot2(wu.p[0], hu.p[0], a0);
      a1 = fdot2(wu.p[1], hu.p[1], a1);
      a2 = fdot2(wu.p[2], hu.p[2], a2);
      a3 = fdot2(wu.p[3], hu.p[3], a3);
    }
#pragma unroll
    for (int i = 0; i < KLDSC; ++i) {
      union { f16x8 v; f16x2 p[4]; } hu;
      hu.v = h8[KREGC + i];
      a0 = fdot2(Wl[i * 4 + 0][tid], hu.p[0], a0);
      a1 = fdot2(Wl[i * 4 + 1][tid], hu.p[1], a1);
      a2 = fdot2(Wl[i * 4 + 2][tid], hu.p[2], a2);
      a3 = fdot2(Wl[i * 4 + 3][tid], hu.p[3], a3);
    }
    float acc = (a0 + a1) + (a2 + a3);
    // tanh(x) = 1 - 2/(exp(2x)+1); branch-free, handles +-inf saturation
    float e = __expf(2.0f * acc);
    float hnew = 1.0f - 2.0f * __builtin_amdgcn_rcpf(e + 1.0f);
    hlast = hnew;
    f16 hh = (f16)hnew;
    hsb[(size_t)t * 512] = hh;
    hbuf[cur ^ 1][tid] = hh;
    __syncthreads();
    cur ^= 1;
    xv = xn;
  }
  hn[(size_t)b * 512 + tid] = hlast;
}

// ---------------- launch ----------------

extern "C" void kernel_launch(void* const* d_in, const int* in_sizes, int n_in,
                              void* d_out, int out_size, void* d_ws, size_t ws_size,
                              hipStream_t stream) {
  const float* x    = (const float*)d_in[0];
  const float* h0   = (const float*)d_in[1];
  const float* W_xh = (const float*)d_in[2];
  const float* b_xh = (const float*)d_in[3];
  const float* W_hh = (const float*)d_in[4];
  const float* b_hh = (const float*)d_in[5];
  const float* W_hy = (const float*)d_in[6];
  const float* b_hy = (const float*)d_in[7];

  const int H = 512;
  const int B = in_sizes[1] / H;            // 64
  const int T = in_sizes[0] / (B * H);      // 1024
  const int M = B * T;                      // 65536

  float* out = (float*)d_out;               // y [M][512] then h_n [B][512]
  float* xp  = out;                         // reuse y region as xp scratch
  float* hn  = out + (size_t)M * H;

  char* w = (char*)d_ws;
  f16*   hs     = (f16*)w;                                  // M*H*2 bytes
  f16*   Wxh_h  = (f16*)(w + (size_t)M * H * 2);
  f16*   Whh_h  = Wxh_h + H * H;
  f16*   Why_h  = Whh_h + H * H;
  float* biasc  = (float*)(Why_h + H * H);

  const int WN = H * H;  // 262144
  cvt_f32_to_f16<<<WN / 1024, 256, 0, stream>>>(W_xh, Wxh_h, WN);
  cvt_f32_to_f16<<<WN / 1024, 256, 0, stream>>>(W_hh, Whh_h, WN);
  cvt_f32_to_f16<<<WN / 1024, 256, 0, stream>>>(W_hy, Why_h, WN);
  bias_comb_kernel<<<2, 256, 0, stream>>>(b_xh, b_hh, biasc, H);

  // xp = x @ W_xh^T + (b_xh + b_hh)   (written into d_out)
  gemm_f16_kernel<true><<<dim3(H / BN, M / BM), 256, 0, stream>>>(
      x, Wxh_h, biasc, xp, M, H, H);

  // sequential scan; writes hs (f16, ws) and h_n (f32, d_out tail)
  rnn_scan_kernel<<<B, RT, 0, stream>>>(Whh_h, h0, xp, hs, hn, T);

  // y = hs @ W_hy^T + b_hy   (overwrites xp region of d_out)
  gemm_f16_kernel<false><<<dim3(H / BN, M / BM), 256, 0, stream>>>(
      hs, Why_h, b_hy, out, M, H, H);
}